// Round 2
// baseline (4953.548 us; speedup 1.0000x reference)
//
#include <hip/hip_runtime.h>

// ---------------------------------------------------------------------------
// IntegerCifar10Net: 4-bit quantized CNN, B=512, CIFAR shapes.
// All post-layer-1 arithmetic is EXACT integer math (acts 0..7, weights -7..7,
// sums < 2^24 so fp32 FMA accumulation is exact). Layer-1 conv accumulates in
// float64 to match the fp64 numpy reference's rounding decisions. Affine+quant
// epilogue in float64 with rint (round-half-even).
// Activations stored as uint8 (value = 7 * real_activation).
// ---------------------------------------------------------------------------

// workspace layout (bytes)
#define WS_W1   0u
#define WS_W2   65536u
#define WS_W3   131072u
#define WS_W4   262144u
#define WS_W5   524288u
#define WS_W6   1048576u
#define WS_WF1  2097152u
#define WS_WF2  4194304u
#define WS_BUFA 5242880u
#define WS_BUFB 41943040u

static __device__ __forceinline__ float  fmaT(float a, float b, float c)  { return fmaf(a, b, c); }
static __device__ __forceinline__ double fmaT(double a, double b, double c){ return fma(a, b, c); }

// ---------------------------------------------------------------------------
// weight quantization: q = rint(clip(w,-1,1)*7)  (int8)
// ---------------------------------------------------------------------------
__global__ void quantw_k(const float* __restrict__ w, signed char* __restrict__ q, int n) {
    int i = blockIdx.x * 256 + threadIdx.x;
    if (i < n) {
        double t = fmin(fmax((double)w[i], -1.0), 1.0) * 7.0;
        q[i] = (signed char)(int)rint(t);
    }
}

// ---------------------------------------------------------------------------
// direct 3x3 s1 p1 conv, fused affine+quant+relu (+optional 2x2 maxpool).
// Thread: 2x2 pixel block x 4 consecutive output channels.
// Block: 256 threads = 64 spatial threads x 4 co-groups (16 co per block).
// FIRST layer accumulates in double (match fp64 reference); others fp32-exact.
// ---------------------------------------------------------------------------
template<int CI, int CO, int H, int W, bool POOL, bool FIRST, int CIC, typename ACC>
__global__ __launch_bounds__(256) void conv_k(
    const void* __restrict__ in_, const signed char* __restrict__ wq,
    const float* __restrict__ gvec, const float* __restrict__ bvec,
    unsigned char* __restrict__ out)
{
    __shared__ float wlds[16 * CIC * 9];   // [lco][lci][tap]

    const int tid = threadIdx.x;
    const int sp  = tid & 63;
    const int cg  = tid >> 6;

    constexpr int nxb = W / 2;
    constexpr int bpi = (W / 2) * (H / 2);

    const int gsp = blockIdx.x * 64 + sp;
    const int b   = gsp / bpi;
    const int rem = gsp - b * bpi;
    const int yb  = rem / nxb;
    const int xb  = rem - yb * nxb;
    const int y0  = yb * 2, x0 = xb * 2;

    const int co_base = blockIdx.y * 16;
    const int co0     = co_base + cg * 4;

    const float*         inF = (const float*)in_;
    const unsigned char* inU = (const unsigned char*)in_;

    ACC acc[4][4];   // [l][pixel]
#pragma unroll
    for (int l = 0; l < 4; ++l)
#pragma unroll
        for (int p = 0; p < 4; ++p) acc[l][p] = (ACC)0;

    for (int ci0 = 0; ci0 < CI; ci0 += CIC) {
        __syncthreads();
        for (int i = tid; i < 16 * CIC * 9; i += 256) {
            int lco = i / (CIC * 9);
            int r2  = i - lco * (CIC * 9);
            int lci = r2 / 9;
            int tap = r2 - lci * 9;
            wlds[i] = (float)wq[((co_base + lco) * CI + (ci0 + lci)) * 9 + tap];
        }
        __syncthreads();

        for (int lci = 0; lci < CIC; ++lci) {
            const int ci   = ci0 + lci;
            const int base = (b * CI + ci) * (H * W);

            ACC a[4][4];
#pragma unroll
            for (int iy = 0; iy < 4; ++iy) {
                const int y   = y0 - 1 + iy;
                const bool yok = ((unsigned)y < (unsigned)H);
#pragma unroll
                for (int ix = 0; ix < 4; ++ix) {
                    const int x  = x0 - 1 + ix;
                    const bool ok = yok && ((unsigned)x < (unsigned)W);
                    const int idx = base + y * W + x;
                    ACC v = (ACC)0;
                    if (ok) v = FIRST ? (ACC)inF[idx] : (ACC)inU[idx];
                    a[iy][ix] = v;
                }
            }

#pragma unroll
            for (int l = 0; l < 4; ++l) {
                const float* wrow = &wlds[((cg * 4 + l) * CIC + lci) * 9];
#pragma unroll
                for (int ky = 0; ky < 3; ++ky) {
#pragma unroll
                    for (int kx = 0; kx < 3; ++kx) {
                        const ACC wv = (ACC)wrow[ky * 3 + kx];
                        acc[l][0] = fmaT(wv, a[ky    ][kx    ], acc[l][0]);
                        acc[l][1] = fmaT(wv, a[ky    ][kx + 1], acc[l][1]);
                        acc[l][2] = fmaT(wv, a[ky + 1][kx    ], acc[l][2]);
                        acc[l][3] = fmaT(wv, a[ky + 1][kx + 1], acc[l][3]);
                    }
                }
            }
        }
    }

    // epilogue: y = (s/scale)*g + b ; t=clip(y,-1,1)*7 ; r=rint(t) ; relu
    const double scale = FIRST ? 7.0 : 49.0;
#pragma unroll
    for (int l = 0; l < 4; ++l) {
        const int co = co0 + l;
        const double gg = (double)gvec[co];
        const double bb = (double)bvec[co];
        int r[4];
#pragma unroll
        for (int p = 0; p < 4; ++p) {
            double conv = (double)acc[l][p] / scale;
            double y    = conv * gg + bb;
            double t    = fmin(fmax(y, -1.0), 1.0) * 7.0;
            int q       = (int)rint(t);
            r[p] = q > 0 ? q : 0;
        }
        if (POOL) {
            int m = max(max(r[0], r[1]), max(r[2], r[3]));
            out[((b * CO + co) * (H / 2) + yb) * (W / 2) + xb] = (unsigned char)m;
        } else {
            const int o = (b * CO + co) * (H * W) + y0 * W + x0;
            out[o]         = (unsigned char)r[0];
            out[o + 1]     = (unsigned char)r[1];
            out[o + W]     = (unsigned char)r[2];
            out[o + W + 1] = (unsigned char)r[3];
        }
    }
}

// ---------------------------------------------------------------------------
// FC1: (512x4096) @ (512x4096)^T, tiled 16x16, exact fp32 integer FMA.
// ---------------------------------------------------------------------------
__global__ __launch_bounds__(256) void fc1_k(
    const unsigned char* __restrict__ h, const signed char* __restrict__ wq,
    const float* __restrict__ gvec, const float* __restrict__ bvec,
    unsigned char* __restrict__ out)
{
    __shared__ float As[16][68];
    __shared__ float Bs[16][68];

    const int tid = threadIdx.x;
    const int tj  = tid & 15;
    const int tb  = tid >> 4;
    const int b0  = blockIdx.x * 16;
    const int j0  = blockIdx.y * 16;

    float acc = 0.f;
    for (int k0 = 0; k0 < 4096; k0 += 64) {
        __syncthreads();
#pragma unroll
        for (int q = 0; q < 4; ++q) {
            const int kk = tj * 4 + q;
            As[tb][kk] = (float)h[(b0 + tb) * 4096 + k0 + kk];
            Bs[tb][kk] = (float)wq[(j0 + tb) * 4096 + k0 + kk];
        }
        __syncthreads();
#pragma unroll
        for (int kk = 0; kk < 64; ++kk)
            acc = fmaf(As[tb][kk], Bs[tj][kk], acc);
    }

    const int j = j0 + tj;
    double y = ((double)acc / 49.0) * (double)gvec[j] + (double)bvec[j];
    double t = fmin(fmax(y, -1.0), 1.0) * 7.0;
    int q = (int)rint(t);
    q = q > 0 ? q : 0;
    out[(b0 + tb) * 512 + j] = (unsigned char)q;
}

// ---------------------------------------------------------------------------
// FC2: (512x512) @ (10x512)^T -> final output (float, value r/7)
// ---------------------------------------------------------------------------
__global__ __launch_bounds__(256) void fc2_k(
    const unsigned char* __restrict__ h, const signed char* __restrict__ wq,
    const float* __restrict__ gvec, const float* __restrict__ bvec,
    float* __restrict__ out)
{
    const int gid = blockIdx.x * 256 + threadIdx.x;
    const int b = gid >> 4;
    const int n = gid & 15;
    if (b >= 512 || n >= 10) return;

    int s = 0;
    for (int k = 0; k < 512; ++k)
        s += (int)h[b * 512 + k] * (int)wq[n * 512 + k];

    double y = ((double)s / 49.0) * (double)gvec[n] + (double)bvec[n];
    double t = fmin(fmax(y, -1.0), 1.0) * 7.0;
    double r = rint(t);
    out[b * 10 + n] = (float)(r / 7.0);
}

// ---------------------------------------------------------------------------
template<int CI, int CO, int H, int W, bool POOL, bool FIRST, int CIC, typename ACC>
static void launch_conv(const void* in, const signed char* wq, const float* g,
                        const float* b, unsigned char* out, hipStream_t s)
{
    constexpr int bpi = (W / 2) * (H / 2);
    dim3 grid((512 * bpi) / 64, CO / 16);
    hipLaunchKernelGGL((conv_k<CI, CO, H, W, POOL, FIRST, CIC, ACC>),
                       grid, dim3(256), 0, s, in, wq, g, b, out);
}

extern "C" void kernel_launch(void* const* d_in, const int* in_sizes, int n_in,
                              void* d_out, int out_size, void* d_ws, size_t ws_size,
                              hipStream_t stream) {
    const float* x   = (const float*)d_in[0];
    const float* w1  = (const float*)d_in[1];
    const float* g1  = (const float*)d_in[2];
    const float* b1  = (const float*)d_in[3];
    const float* w2  = (const float*)d_in[4];
    const float* g2  = (const float*)d_in[5];
    const float* b2  = (const float*)d_in[6];
    const float* w3  = (const float*)d_in[7];
    const float* g3  = (const float*)d_in[8];
    const float* b3  = (const float*)d_in[9];
    const float* w4  = (const float*)d_in[10];
    const float* g4  = (const float*)d_in[11];
    const float* b4  = (const float*)d_in[12];
    const float* w5  = (const float*)d_in[13];
    const float* g5  = (const float*)d_in[14];
    const float* b5  = (const float*)d_in[15];
    const float* w6  = (const float*)d_in[16];
    const float* g6  = (const float*)d_in[17];
    const float* b6  = (const float*)d_in[18];
    const float* wf1 = (const float*)d_in[19];
    const float* gf1 = (const float*)d_in[20];
    const float* bf1 = (const float*)d_in[21];
    const float* wf2 = (const float*)d_in[22];
    const float* gf2 = (const float*)d_in[23];
    const float* bf2 = (const float*)d_in[24];

    char* ws = (char*)d_ws;
    signed char* qw1  = (signed char*)(ws + WS_W1);
    signed char* qw2  = (signed char*)(ws + WS_W2);
    signed char* qw3  = (signed char*)(ws + WS_W3);
    signed char* qw4  = (signed char*)(ws + WS_W4);
    signed char* qw5  = (signed char*)(ws + WS_W5);
    signed char* qw6  = (signed char*)(ws + WS_W6);
    signed char* qwf1 = (signed char*)(ws + WS_WF1);
    signed char* qwf2 = (signed char*)(ws + WS_WF2);
    unsigned char* bufA = (unsigned char*)(ws + WS_BUFA);
    unsigned char* bufB = (unsigned char*)(ws + WS_BUFB);

    struct { const float* w; signed char* q; int n; } qs[8] = {
        {w1,  qw1,  64 * 3 * 9},
        {w2,  qw2,  64 * 64 * 9},
        {w3,  qw3,  128 * 64 * 9},
        {w4,  qw4,  128 * 128 * 9},
        {w5,  qw5,  256 * 128 * 9},
        {w6,  qw6,  256 * 256 * 9},
        {wf1, qwf1, 512 * 4096},
        {wf2, qwf2, 10 * 512},
    };
    for (int i = 0; i < 8; ++i) {
        int blocks = (qs[i].n + 255) / 256;
        hipLaunchKernelGGL(quantw_k, dim3(blocks), dim3(256), 0, stream,
                           qs[i].w, qs[i].q, qs[i].n);
    }

    // conv stack (layer 1 in fp64 to match fp64 reference rounding decisions)
    launch_conv<3,   64,  32, 32, false, true,  3,  double>(x,    qw1, g1, b1, bufA, stream);
    launch_conv<64,  64,  32, 32, true,  false, 32, float >(bufA, qw2, g2, b2, bufB, stream);
    launch_conv<64,  128, 16, 16, false, false, 32, float >(bufB, qw3, g3, b3, bufA, stream);
    launch_conv<128, 128, 16, 16, true,  false, 32, float >(bufA, qw4, g4, b4, bufB, stream);
    launch_conv<128, 256, 8,  8,  false, false, 32, float >(bufB, qw5, g5, b5, bufA, stream);
    launch_conv<256, 256, 8,  8,  true,  false, 32, float >(bufA, qw6, g6, b6, bufB, stream);

    // FC head
    hipLaunchKernelGGL(fc1_k, dim3(32, 32), dim3(256), 0, stream,
                       bufB, qwf1, gf1, bf1, bufA);
    hipLaunchKernelGGL(fc2_k, dim3(32), dim3(256), 0, stream,
                       bufA, qwf2, gf2, bf2, (float*)d_out);
}

// Round 3
// 632.245 us; speedup vs baseline: 7.8349x; 7.8349x over previous
//
#include <hip/hip_runtime.h>

// ---------------------------------------------------------------------------
// IntegerCifar10Net: 4-bit quantized CNN, B=512.
// Post-layer-1 math is EXACT integer arithmetic (acts 0..7, weights -7..7,
// partial sums < 2^24) -> run it on bf16 MFMA (exact in fp32 accumulators).
// Layer 1 stays fp64 (continuous input; must match fp64 numpy reference
// rounding decisions -- proven bit-exact in round 2).
// Inter-layer activations: NHWC u8 (value = 7 * real activation).
// Epilogue: fp64 affine + rint quant (identical expressions to round 2).
// ---------------------------------------------------------------------------

typedef __attribute__((ext_vector_type(8))) short short8;
typedef __attribute__((ext_vector_type(4))) float f32x4;

// workspace offsets (bytes)
#define O_QW1    0u          // 1728 i8   conv1 weights [64][3][9]
#define O_QWF2   4096u       // 5120 i8   fc2 weights [10][512]
#define O_QWT2   16384u      // 73728  bf16 [64][9][64]
#define O_QWT3   90112u      // 147456 bf16 [128][9][64]
#define O_QWT4   237568u     // 294912 bf16 [128][9][128]
#define O_QWT5   532480u     // 589824 bf16 [256][9][128]
#define O_QWT6   1122304u    // 1179648 bf16 [256][9][256]
#define O_QWF1T  2301952u    // 4194304 bf16 [512][4096] k reordered to NHWC
#define O_BUFA   6496256u    // 33.5 MB
#define O_BUFB   40050688u   // 8.4 MB   (total 46.2 MB)

// ---------------------------------------------------------------------------
__global__ void quantw_k(const float* __restrict__ w, signed char* __restrict__ q, int n) {
    int i = blockIdx.x * 256 + threadIdx.x;
    if (i < n) {
        double t = fmin(fmax((double)w[i], -1.0), 1.0) * 7.0;
        q[i] = (signed char)(int)rint(t);
    }
}

// conv weights: fp32 [CO][CI][3][3] -> bf16 [CO][9][CI]
__global__ void quantw_t_k(const float* __restrict__ w, unsigned short* __restrict__ o,
                           int CI, int n) {
    int i = blockIdx.x * 256 + threadIdx.x;
    if (i < n) {
        int co  = i / (9 * CI);
        int rem = i - co * 9 * CI;
        int t   = rem / CI;
        int ci  = rem - t * CI;
        double v = fmin(fmax((double)w[(co * CI + ci) * 9 + t], -1.0), 1.0) * 7.0;
        float f  = (float)(int)rint(v);
        o[i] = (unsigned short)(__float_as_uint(f) >> 16);
    }
}

// fc1 weights: fp32 [512][4096 nchw-k] -> bf16 [512][4096 nhwc-k]
__global__ void quantw_fc1_k(const float* __restrict__ w, unsigned short* __restrict__ o) {
    int i = blockIdx.x * 256 + threadIdx.x;
    if (i < 512 * 4096) {
        int j  = i >> 12;
        int kn = i & 4095;
        int px = kn >> 8;          // y*4+x
        int c  = kn & 255;
        int ko = c * 16 + px;      // nchw flat index
        double v = fmin(fmax((double)w[j * 4096 + ko], -1.0), 1.0) * 7.0;
        float f  = (float)(int)rint(v);
        o[i] = (unsigned short)(__float_as_uint(f) >> 16);
    }
}

// ---------------------------------------------------------------------------
// conv1: 3->64, 32x32, fp64-exact, NHWC u8 output
// ---------------------------------------------------------------------------
__global__ __launch_bounds__(256) void conv1_k(
    const float* __restrict__ x, const signed char* __restrict__ wq,
    const float* __restrict__ gvec, const float* __restrict__ bvec,
    unsigned char* __restrict__ out)
{
    __shared__ float wlds[16 * 27];
    const int tid = threadIdx.x;
    const int sp  = tid & 63;
    const int cg  = tid >> 6;
    const int gsp = blockIdx.x * 64 + sp;
    const int b   = gsp >> 8;
    const int rem = gsp & 255;
    const int yb  = rem >> 4, xb = rem & 15;
    const int y0  = yb * 2, x0 = xb * 2;
    const int co_base = blockIdx.y * 16;
    const int co0 = co_base + cg * 4;

    for (int i = tid; i < 16 * 27; i += 256)
        wlds[i] = (float)wq[co_base * 27 + i];
    __syncthreads();

    double acc[4][4];
#pragma unroll
    for (int l = 0; l < 4; ++l)
#pragma unroll
        for (int p = 0; p < 4; ++p) acc[l][p] = 0.0;

    for (int ci = 0; ci < 3; ++ci) {
        const int base = (b * 3 + ci) * 1024;
        double a[4][4];
#pragma unroll
        for (int iy = 0; iy < 4; ++iy) {
            const int y = y0 - 1 + iy;
            const bool yok = ((unsigned)y < 32u);
#pragma unroll
            for (int ix = 0; ix < 4; ++ix) {
                const int xx = x0 - 1 + ix;
                const bool ok = yok && ((unsigned)xx < 32u);
                a[iy][ix] = ok ? (double)x[base + y * 32 + xx] : 0.0;
            }
        }
#pragma unroll
        for (int l = 0; l < 4; ++l) {
            const float* wrow = &wlds[((cg * 4 + l) * 3 + ci) * 9];
#pragma unroll
            for (int ky = 0; ky < 3; ++ky)
#pragma unroll
                for (int kx = 0; kx < 3; ++kx) {
                    const double wv = (double)wrow[ky * 3 + kx];
                    acc[l][0] = fma(wv, a[ky    ][kx    ], acc[l][0]);
                    acc[l][1] = fma(wv, a[ky    ][kx + 1], acc[l][1]);
                    acc[l][2] = fma(wv, a[ky + 1][kx    ], acc[l][2]);
                    acc[l][3] = fma(wv, a[ky + 1][kx + 1], acc[l][3]);
                }
        }
    }

#pragma unroll
    for (int l = 0; l < 4; ++l) {
        const int co = co0 + l;
        const double gg = (double)gvec[co];
        const double bb = (double)bvec[co];
#pragma unroll
        for (int p = 0; p < 4; ++p) {
            double conv = acc[l][p] / 7.0;
            double y = conv * gg + bb;
            double t = fmin(fmax(y, -1.0), 1.0) * 7.0;
            int q = (int)rint(t);
            q = q > 0 ? q : 0;
            const int Y = y0 + (p >> 1), X = x0 + (p & 1);
            out[((b * 32 + Y) * 32 + X) * 64 + co] = (unsigned char)q;
        }
    }
}

// ---------------------------------------------------------------------------
// MFMA implicit-GEMM conv: NHWC u8 in, bf16 [CO][9][CI] weights, NHWC u8 out.
// Block: 256 thr = 4 waves; 64 co x 256 px (IPB=1: one 16x16 region;
// IPB=4: 4 images of 8x8). Wave: 64 co x 64 px = 4x4 fragments of 16x16x32.
// Morton px->m mapping makes each lane's 4 acc regs a 2x2 pool window.
// ---------------------------------------------------------------------------
template<int CI, int CO, int H, int W, bool POOL, int IPB>
__global__ __launch_bounds__(256, 2) void conv_mfma_k(
    const unsigned char* __restrict__ in, const unsigned short* __restrict__ wt,
    const float* __restrict__ gvec, const float* __restrict__ bvec,
    unsigned char* __restrict__ out)
{
    constexpr int ATX   = (IPB == 1) ? 18 : 10;
    constexpr int APX   = ATX * ATX;
    constexpr int AELEM = IPB * APX * 32;
    constexpr int WOFF  = AELEM;
    constexpr int NPASS = CI / 32;

    __shared__ short lds[AELEM + 64 * 9 * 32];

    const int tid = threadIdx.x;
    const int l   = tid & 63;
    const int w   = tid >> 6;
    const int n   = l & 15;
    const int q   = l >> 4;

    int img = 0, regY0 = 0, regX0 = 0, wy8 = 0, wx8 = 0, tileoff = 0;
    if (IPB == 1) {
        constexpr int rpw = W / 16;
        constexpr int rpi = (H / 16) * rpw;
        img   = blockIdx.x / rpi;
        int r = blockIdx.x % rpi;
        regY0 = (r / rpw) * 16;
        regX0 = (r % rpw) * 16;
        wy8 = (w >> 1) * 8; wx8 = (w & 1) * 8;
    } else {
        tileoff = w * APX * 32;
    }
    const int co_base = blockIdx.y * 64;

    const int ly = ((n >> 3) & 1) * 2 + ((n >> 1) & 1);
    const int lx = ((n >> 2) & 1) * 2 + (n & 1);

    int abase[4], wbase[4];
#pragma unroll
    for (int ps = 0; ps < 4; ++ps) {
        int ay0 = wy8 + (ps >> 1) * 4 + ly;
        int ax0 = wx8 + (ps & 1) * 4 + lx;
        abase[ps] = tileoff + (ay0 * ATX + ax0) * 32 + q * 8;
    }
#pragma unroll
    for (int cs = 0; cs < 4; ++cs)
        wbase[cs] = WOFF + (cs * 16 + n) * 288 + q * 8;

    f32x4 acc[4][4];
#pragma unroll
    for (int ps = 0; ps < 4; ++ps)
#pragma unroll
        for (int cs = 0; cs < 4; ++cs)
            acc[ps][cs] = (f32x4)0.f;

    for (int pass = 0; pass < NPASS; ++pass) {
        const int cib = pass * 32;
        __syncthreads();
        // --- activation staging: u8 NHWC -> bf16 LDS [tile][px][ci32] ---
        constexpr int AITEMS = IPB * APX * 8;
        for (int i = tid; i < AITEMS; i += 256) {
            int tile, px, grp;
            if (IPB == 1) { tile = 0; px = i >> 3; grp = i & 7; }
            else { tile = i / (APX * 8); int r2 = i - tile * (APX * 8); px = r2 >> 3; grp = r2 & 7; }
            int gy = regY0 - 1 + px / ATX;
            int gx = regX0 - 1 + px % ATX;
            int bimg = (IPB == 1) ? img : ((int)blockIdx.x * 4 + tile);
            unsigned int v = 0;
            if ((unsigned)gy < (unsigned)H && (unsigned)gx < (unsigned)W)
                v = *(const unsigned int*)&in[((bimg * H + gy) * W + gx) * CI + cib + grp * 4];
            unsigned int f0 = __float_as_uint((float)(v & 0xff));
            unsigned int f1 = __float_as_uint((float)((v >> 8) & 0xff));
            unsigned int f2 = __float_as_uint((float)((v >> 16) & 0xff));
            unsigned int f3 = __float_as_uint((float)(v >> 24));
            uint2 o;
            o.x = (f0 >> 16) | (f1 & 0xffff0000u);
            o.y = (f2 >> 16) | (f3 & 0xffff0000u);
            *(uint2*)&lds[tile * (APX * 32) + px * 32 + grp * 4] = o;
        }
        // --- weight staging: bf16 [co][tap][ci] chunk -> LDS ---
        for (int i = tid; i < 4608; i += 256) {
            int row = i >> 3, grp = i & 7;
            int co_l = row / 9, tap = row - co_l * 9;
            uint2 v = *(const uint2*)&wt[((co_base + co_l) * 9 + tap) * CI + cib + grp * 4];
            *(uint2*)&lds[WOFF + row * 32 + grp * 4] = v;
        }
        __syncthreads();

#pragma unroll
        for (int tap = 0; tap < 9; ++tap) {
            const int toff = ((tap / 3) * ATX + (tap % 3)) * 32;
            short8 bf[4], af[4];
#pragma unroll
            for (int cs = 0; cs < 4; ++cs)
                bf[cs] = *(const short8*)&lds[wbase[cs] + tap * 32];
#pragma unroll
            for (int ps = 0; ps < 4; ++ps)
                af[ps] = *(const short8*)&lds[abase[ps] + toff];
#pragma unroll
            for (int ps = 0; ps < 4; ++ps)
#pragma unroll
                for (int cs = 0; cs < 4; ++cs)
                    acc[ps][cs] = __builtin_amdgcn_mfma_f32_16x16x32_bf16(
                        af[ps], bf[cs], acc[ps][cs], 0, 0, 0);
        }
    }

    // --- epilogue: fp64 affine+quant+relu, optional intra-lane 2x2 pool ---
    const int bimg = (IPB == 1) ? img : ((int)blockIdx.x * 4 + w);
#pragma unroll
    for (int cs = 0; cs < 4; ++cs) {
        const int co = co_base + cs * 16 + n;
        const double gg = (double)gvec[co];
        const double bb = (double)bvec[co];
#pragma unroll
        for (int ps = 0; ps < 4; ++ps) {
            const int Yb = regY0 + wy8 + (ps >> 1) * 4 + (q >> 1) * 2;
            const int Xb = regX0 + wx8 + (ps & 1) * 4 + (q & 1) * 2;
            int r4[4];
#pragma unroll
            for (int r = 0; r < 4; ++r) {
                double conv = (double)acc[ps][cs][r] / 49.0;
                double y = conv * gg + bb;
                double t = fmin(fmax(y, -1.0), 1.0) * 7.0;
                int qi = (int)rint(t);
                r4[r] = qi > 0 ? qi : 0;
            }
            if (POOL) {
                int m = max(max(r4[0], r4[1]), max(r4[2], r4[3]));
                out[((bimg * (H / 2) + (Yb >> 1)) * (W / 2) + (Xb >> 1)) * CO + co] = (unsigned char)m;
            } else {
#pragma unroll
                for (int r = 0; r < 4; ++r) {
                    const int Y = Yb + (r >> 1), X = Xb + (r & 1);
                    out[((bimg * H + Y) * W + X) * CO + co] = (unsigned char)r4[r];
                }
            }
        }
    }
}

// ---------------------------------------------------------------------------
static __device__ __forceinline__ short8 cvt_u8x8_bf16(uint2 v) {
    union { short8 s; unsigned int u[4]; } r;
    r.u[0] = (__float_as_uint((float)(v.x & 0xff)) >> 16) |
             (__float_as_uint((float)((v.x >> 8) & 0xff)) & 0xffff0000u);
    r.u[1] = (__float_as_uint((float)((v.x >> 16) & 0xff)) >> 16) |
             (__float_as_uint((float)(v.x >> 24)) & 0xffff0000u);
    r.u[2] = (__float_as_uint((float)(v.y & 0xff)) >> 16) |
             (__float_as_uint((float)((v.y >> 8) & 0xff)) & 0xffff0000u);
    r.u[3] = (__float_as_uint((float)((v.y >> 16) & 0xff)) >> 16) |
             (__float_as_uint((float)(v.y >> 24)) & 0xffff0000u);
    return r.s;
}

// FC1: h[512][4096] u8 x wt[512][4096] bf16 -> u8 [512][512]
// Block: 32x32 output tile, 4 waves split K=4096 into 1024 each, LDS reduce.
__global__ __launch_bounds__(256, 2) void fc1_mfma_k(
    const unsigned char* __restrict__ h, const unsigned short* __restrict__ wt,
    const float* __restrict__ gvec, const float* __restrict__ bvec,
    unsigned char* __restrict__ out)
{
    __shared__ float red[4096];
    const int tid = threadIdx.x;
    const int l = tid & 63, w = tid >> 6;
    const int n = l & 15, q = l >> 4;
    const int m0 = blockIdx.x * 32, n0 = blockIdx.y * 32;

    f32x4 acc[2][2];
#pragma unroll
    for (int a = 0; a < 2; ++a)
#pragma unroll
        for (int b = 0; b < 2; ++b) acc[a][b] = (f32x4)0.f;

    const int kb = w * 1024;
    for (int ks = 0; ks < 32; ++ks) {
        const int k = kb + ks * 32 + q * 8;
        short8 af[2], bf[2];
#pragma unroll
        for (int ms = 0; ms < 2; ++ms) {
            uint2 v = *(const uint2*)&h[(m0 + ms * 16 + n) * 4096 + k];
            af[ms] = cvt_u8x8_bf16(v);
        }
#pragma unroll
        for (int ns = 0; ns < 2; ++ns)
            bf[ns] = *(const short8*)&wt[(n0 + ns * 16 + n) * 4096 + k];
#pragma unroll
        for (int ms = 0; ms < 2; ++ms)
#pragma unroll
            for (int ns = 0; ns < 2; ++ns)
                acc[ms][ns] = __builtin_amdgcn_mfma_f32_16x16x32_bf16(
                    af[ms], bf[ns], acc[ms][ns], 0, 0, 0);
    }

#pragma unroll
    for (int ms = 0; ms < 2; ++ms)
#pragma unroll
        for (int ns = 0; ns < 2; ++ns)
#pragma unroll
            for (int r = 0; r < 4; ++r)
                red[w * 1024 + (ms * 16 + q * 4 + r) * 32 + ns * 16 + n] = acc[ms][ns][r];
    __syncthreads();

#pragma unroll
    for (int j = 0; j < 4; ++j) {
        const int e = tid * 4 + j;
        float s = red[e] + red[1024 + e] + red[2048 + e] + red[3072 + e];
        const int ml = e >> 5, nl = e & 31;
        const int co = n0 + nl;
        double y = ((double)s / 49.0) * (double)gvec[co] + (double)bvec[co];
        double t = fmin(fmax(y, -1.0), 1.0) * 7.0;
        int qi = (int)rint(t);
        qi = qi > 0 ? qi : 0;
        out[(m0 + ml) * 512 + co] = (unsigned char)qi;
    }
}

// FC2: tiny
__global__ __launch_bounds__(256) void fc2_k(
    const unsigned char* __restrict__ h, const signed char* __restrict__ wq,
    const float* __restrict__ gvec, const float* __restrict__ bvec,
    float* __restrict__ out)
{
    const int gid = blockIdx.x * 256 + threadIdx.x;
    const int b = gid >> 4;
    const int n = gid & 15;
    if (b >= 512 || n >= 10) return;
    int s = 0;
    for (int k = 0; k < 512; ++k)
        s += (int)h[b * 512 + k] * (int)wq[n * 512 + k];
    double y = ((double)s / 49.0) * (double)gvec[n] + (double)bvec[n];
    double t = fmin(fmax(y, -1.0), 1.0) * 7.0;
    double r = rint(t);
    out[b * 10 + n] = (float)(r / 7.0);
}

// ---------------------------------------------------------------------------
extern "C" void kernel_launch(void* const* d_in, const int* in_sizes, int n_in,
                              void* d_out, int out_size, void* d_ws, size_t ws_size,
                              hipStream_t stream) {
    const float* x   = (const float*)d_in[0];
    const float* w1  = (const float*)d_in[1];
    const float* g1  = (const float*)d_in[2];
    const float* b1  = (const float*)d_in[3];
    const float* w2  = (const float*)d_in[4];
    const float* g2  = (const float*)d_in[5];
    const float* b2  = (const float*)d_in[6];
    const float* w3  = (const float*)d_in[7];
    const float* g3  = (const float*)d_in[8];
    const float* b3  = (const float*)d_in[9];
    const float* w4  = (const float*)d_in[10];
    const float* g4  = (const float*)d_in[11];
    const float* b4  = (const float*)d_in[12];
    const float* w5  = (const float*)d_in[13];
    const float* g5  = (const float*)d_in[14];
    const float* b5  = (const float*)d_in[15];
    const float* w6  = (const float*)d_in[16];
    const float* g6  = (const float*)d_in[17];
    const float* b6  = (const float*)d_in[18];
    const float* wf1 = (const float*)d_in[19];
    const float* gf1 = (const float*)d_in[20];
    const float* bf1 = (const float*)d_in[21];
    const float* wf2 = (const float*)d_in[22];
    const float* gf2 = (const float*)d_in[23];
    const float* bf2 = (const float*)d_in[24];

    char* ws = (char*)d_ws;
    signed char*    qw1   = (signed char*)(ws + O_QW1);
    signed char*    qwf2  = (signed char*)(ws + O_QWF2);
    unsigned short* qwt2  = (unsigned short*)(ws + O_QWT2);
    unsigned short* qwt3  = (unsigned short*)(ws + O_QWT3);
    unsigned short* qwt4  = (unsigned short*)(ws + O_QWT4);
    unsigned short* qwt5  = (unsigned short*)(ws + O_QWT5);
    unsigned short* qwt6  = (unsigned short*)(ws + O_QWT6);
    unsigned short* qwf1t = (unsigned short*)(ws + O_QWF1T);
    unsigned char*  bufA  = (unsigned char*)(ws + O_BUFA);
    unsigned char*  bufB  = (unsigned char*)(ws + O_BUFB);

    // weight prep
    hipLaunchKernelGGL(quantw_k, dim3(7),  dim3(256), 0, stream, w1,  qw1,  1728);
    hipLaunchKernelGGL(quantw_k, dim3(20), dim3(256), 0, stream, wf2, qwf2, 5120);
    hipLaunchKernelGGL(quantw_t_k, dim3((36864  + 255) / 256), dim3(256), 0, stream, w2, qwt2, 64,  36864);
    hipLaunchKernelGGL(quantw_t_k, dim3((73728  + 255) / 256), dim3(256), 0, stream, w3, qwt3, 64,  73728);
    hipLaunchKernelGGL(quantw_t_k, dim3((147456 + 255) / 256), dim3(256), 0, stream, w4, qwt4, 128, 147456);
    hipLaunchKernelGGL(quantw_t_k, dim3((294912 + 255) / 256), dim3(256), 0, stream, w5, qwt5, 128, 294912);
    hipLaunchKernelGGL(quantw_t_k, dim3((589824 + 255) / 256), dim3(256), 0, stream, w6, qwt6, 256, 589824);
    hipLaunchKernelGGL(quantw_fc1_k, dim3(8192), dim3(256), 0, stream, wf1, qwf1t);

    // conv stack
    hipLaunchKernelGGL(conv1_k, dim3(2048, 4), dim3(256), 0, stream, x, qw1, g1, b1, bufA);
    hipLaunchKernelGGL((conv_mfma_k<64,  64,  32, 32, true,  1>), dim3(2048, 1), dim3(256), 0, stream, bufA, qwt2, g2, b2, bufB);
    hipLaunchKernelGGL((conv_mfma_k<64,  128, 16, 16, false, 1>), dim3(512,  2), dim3(256), 0, stream, bufB, qwt3, g3, b3, bufA);
    hipLaunchKernelGGL((conv_mfma_k<128, 128, 16, 16, true,  1>), dim3(512,  2), dim3(256), 0, stream, bufA, qwt4, g4, b4, bufB);
    hipLaunchKernelGGL((conv_mfma_k<128, 256, 8,  8,  false, 4>), dim3(128,  4), dim3(256), 0, stream, bufB, qwt5, g5, b5, bufA);
    hipLaunchKernelGGL((conv_mfma_k<256, 256, 8,  8,  true,  4>), dim3(128,  4), dim3(256), 0, stream, bufA, qwt6, g6, b6, bufB);

    // FC head
    hipLaunchKernelGGL(fc1_mfma_k, dim3(16, 16), dim3(256), 0, stream, bufB, qwf1t, gf1, bf1, bufA);
    hipLaunchKernelGGL(fc2_k, dim3(32), dim3(256), 0, stream, bufA, qwf2, gf2, bf2, (float*)d_out);
}

// Round 4
// 376.716 us; speedup vs baseline: 13.1493x; 1.6783x over previous
//
#include <hip/hip_runtime.h>

// ---------------------------------------------------------------------------
// IntegerCifar10Net: 4-bit quantized CNN, B=512.
// Post-layer-1 math is EXACT integer arithmetic (acts 0..7, weights -7..7,
// partial sums < 2^31) -> run it on i8 MFMA (mfma_i32_16x16x64_i8, exact i32
// accumulate, K=64 = 2x bf16 rate, raw u8/i8 staging with no cvt).
// Layer 1 stays fp64 (continuous input; must match fp64 numpy reference) but
// now stages x+weights into LDS as doubles (no per-use cvt, no branches).
// Inter-layer activations: NHWC u8 (value = 7 * real activation).
// Epilogue: fp64 affine + rint quant -- identical expressions to round 2/3
// (proven bit-exact), fed identical integer sums.
// LDS conv layout: 4 k-chunk planes (chunk q at q*PLANE + row*16) to break
// the 64B-row-stride bank aliasing that plagued the round-3 bf16 kernel.
// ---------------------------------------------------------------------------

typedef __attribute__((ext_vector_type(4))) int v4i;

// workspace offsets (bytes)
#define O_QW1    0u          // 1728    i8 conv1 [64][3][9]
#define O_QWF2   4096u       // 5120    i8 fc2   [10][512]
#define O_QWT2   16384u      // 36864   i8 [64][9][64]
#define O_QWT3   65536u      // 73728   i8 [128][9][64]
#define O_QWT4   147456u     // 147456  i8 [128][9][128]
#define O_QWT5   294912u     // 294912  i8 [256][9][128]
#define O_QWT6   589824u     // 589824  i8 [256][9][256]
#define O_QWF1   1179648u    // 2097152 i8 [512][4096] k reordered to NHWC
#define O_BUFA   3276800u    // 33.5 MB
#define O_BUFB   36831232u   // 8.4 MB  (total ~45.2 MB)

// ---------------------------------------------------------------------------
// weight prep
// ---------------------------------------------------------------------------
__global__ void quantw_k(const float* __restrict__ w, signed char* __restrict__ q, int n) {
    int i = blockIdx.x * 256 + threadIdx.x;
    if (i < n) {
        double t = fmin(fmax((double)w[i], -1.0), 1.0) * 7.0;
        q[i] = (signed char)(int)rint(t);
    }
}

// conv weights: fp32 [CO][CI][3][3] -> i8 [CO][9][CI]
__global__ void quantw_t8_k(const float* __restrict__ w, signed char* __restrict__ o,
                            int CI, int n) {
    int i = blockIdx.x * 256 + threadIdx.x;
    if (i < n) {
        int co  = i / (9 * CI);
        int rem = i - co * 9 * CI;
        int t   = rem / CI;
        int ci  = rem - t * CI;
        double v = fmin(fmax((double)w[(co * CI + ci) * 9 + t], -1.0), 1.0) * 7.0;
        o[i] = (signed char)(int)rint(v);
    }
}

// fc1 weights: fp32 [512][4096 nchw-k] -> i8 [512][4096 nhwc-k]
__global__ void quantw_fc1_k(const float* __restrict__ w, signed char* __restrict__ o) {
    int i = blockIdx.x * 256 + threadIdx.x;
    if (i < 512 * 4096) {
        int j  = i >> 12;
        int kn = i & 4095;
        int px = kn >> 8;          // y*4+x
        int c  = kn & 255;
        int ko = c * 16 + px;      // nchw flat index
        double v = fmin(fmax((double)w[j * 4096 + ko], -1.0), 1.0) * 7.0;
        o[i] = (signed char)(int)rint(v);
    }
}

// ---------------------------------------------------------------------------
// conv1: 3->64, 32x32, fp64-exact, NHWC u8 output.
// Block: image b x 8-row slab x 16 co. x tile + weights staged in LDS as
// doubles (cvt once, zero-padded halo -> branch-free inner loop).
// ---------------------------------------------------------------------------
__global__ __launch_bounds__(256) void conv1_k(
    const float* __restrict__ x, const signed char* __restrict__ wq,
    const float* __restrict__ gvec, const float* __restrict__ bvec,
    unsigned char* __restrict__ out)
{
    __shared__ double xs[3 * 10 * 34];   // [ci][10 rows][34 cols], halo included
    __shared__ double wd[16 * 27];       // [lco][ci][tap]

    const int tid  = threadIdx.x;
    const int sp   = tid & 63;
    const int cg   = tid >> 6;
    const int img  = blockIdx.x >> 2;
    const int slab = blockIdx.x & 3;
    const int y0s  = slab * 8;
    const int co_base = blockIdx.y * 16;
    const int yb = sp >> 4, xb = sp & 15;
    const int ysl = yb * 2, x0 = xb * 2;

    for (int i = tid; i < 432; i += 256)
        wd[i] = (double)wq[co_base * 27 + i];
    for (int i = tid; i < 1020; i += 256) {
        int ci = i / 340, r = i - ci * 340;
        int ry = r / 34, rx = r - ry * 34;
        int gy = y0s - 1 + ry, gx = rx - 1;
        double v = 0.0;
        if ((unsigned)gy < 32u && (unsigned)gx < 32u)
            v = (double)x[(img * 3 + ci) * 1024 + gy * 32 + gx];
        xs[i] = v;
    }
    __syncthreads();

    double acc[4][4];
#pragma unroll
    for (int l = 0; l < 4; ++l)
#pragma unroll
        for (int p = 0; p < 4; ++p) acc[l][p] = 0.0;

#pragma unroll
    for (int ci = 0; ci < 3; ++ci) {
        double a[4][4];
#pragma unroll
        for (int iy = 0; iy < 4; ++iy)
#pragma unroll
            for (int ix = 0; ix < 4; ++ix)
                a[iy][ix] = xs[ci * 340 + (ysl + iy) * 34 + (x0 + ix)];
#pragma unroll
        for (int l = 0; l < 4; ++l) {
            const double* wr = &wd[((cg * 4 + l) * 3 + ci) * 9];
#pragma unroll
            for (int ky = 0; ky < 3; ++ky)
#pragma unroll
                for (int kx = 0; kx < 3; ++kx) {
                    const double wv = wr[ky * 3 + kx];
                    acc[l][0] = fma(wv, a[ky    ][kx    ], acc[l][0]);
                    acc[l][1] = fma(wv, a[ky    ][kx + 1], acc[l][1]);
                    acc[l][2] = fma(wv, a[ky + 1][kx    ], acc[l][2]);
                    acc[l][3] = fma(wv, a[ky + 1][kx + 1], acc[l][3]);
                }
        }
    }

#pragma unroll
    for (int l = 0; l < 4; ++l) {
        const int co = co_base + cg * 4 + l;
        const double gg = (double)gvec[co];
        const double bb = (double)bvec[co];
#pragma unroll
        for (int p = 0; p < 4; ++p) {
            double conv = acc[l][p] / 7.0;
            double y = conv * gg + bb;
            double t = fmin(fmax(y, -1.0), 1.0) * 7.0;
            int q = (int)rint(t);
            q = q > 0 ? q : 0;
            const int Y = y0s + ysl + (p >> 1), X = x0 + (p & 1);
            out[((img * 32 + Y) * 32 + X) * 64 + co] = (unsigned char)q;
        }
    }
}

// ---------------------------------------------------------------------------
// i8 MFMA implicit-GEMM conv: NHWC u8 in, i8 [CO][9][CI] weights, NHWC u8 out.
// Block: 256 thr = 4 waves; 64 co x 256 px. K processed in ci-chunks of 64.
// LDS: 4 planes (one per 16B k-chunk q); row r's chunk q lives at
// q*PLANE + r*16 -> quarter-wave b128 reads spread over bank-groups.
// Morton px->m mapping makes each lane's 4 acc regs a 2x2 pool window.
// ---------------------------------------------------------------------------
template<int CI, int CO, int H, int W, bool POOL, int IPB>
__global__ __launch_bounds__(256, 2) void conv_i8_k(
    const unsigned char* __restrict__ in, const signed char* __restrict__ wt,
    const float* __restrict__ gvec, const float* __restrict__ bvec,
    unsigned char* __restrict__ out)
{
    constexpr int ATX    = (IPB == 1) ? 18 : 10;
    constexpr int APX    = ATX * ATX;
    constexpr int APLANE = IPB * APX * 16;       // bytes per act plane
    constexpr int WBASE  = 4 * APLANE;
    constexpr int WPLANE = 576 * 16;             // 64 co x 9 taps rows
    constexpr int NPASS  = CI / 64;

    __shared__ __align__(16) char lds[WBASE + 4 * WPLANE];

    const int tid = threadIdx.x;
    const int l   = tid & 63;
    const int w   = tid >> 6;
    const int n   = l & 15;
    const int q   = l >> 4;

    int img = 0, regY0 = 0, regX0 = 0, wy8 = 0, wx8 = 0, tilepx = 0;
    if (IPB == 1) {
        constexpr int rpw = W / 16;
        constexpr int rpi = (H / 16) * rpw;
        img   = blockIdx.x / rpi;
        int r = blockIdx.x % rpi;
        regY0 = (r / rpw) * 16;
        regX0 = (r % rpw) * 16;
        wy8 = (w >> 1) * 8; wx8 = (w & 1) * 8;
    } else {
        tilepx = w * APX;
    }
    const int co_base = blockIdx.y * 64;

    const int ly = ((n >> 3) & 1) * 2 + ((n >> 1) & 1);
    const int lx = ((n >> 2) & 1) * 2 + (n & 1);

    int abase[4], wbase[4];
#pragma unroll
    for (int ps = 0; ps < 4; ++ps) {
        int ay0 = wy8 + (ps >> 1) * 4 + ly;
        int ax0 = wx8 + (ps & 1) * 4 + lx;
        abase[ps] = q * APLANE + (tilepx + ay0 * ATX + ax0) * 16;
    }
#pragma unroll
    for (int cs = 0; cs < 4; ++cs)
        wbase[cs] = WBASE + q * WPLANE + ((cs * 16 + n) * 9) * 16;

    v4i acc[4][4];
#pragma unroll
    for (int ps = 0; ps < 4; ++ps)
#pragma unroll
        for (int cs = 0; cs < 4; ++cs)
            acc[ps][cs] = (v4i)0;

    for (int pass = 0; pass < NPASS; ++pass) {
        const int cib = pass * 64;
        __syncthreads();
        // --- activation staging: raw u8 NHWC 16B chunks -> plane-split LDS ---
        for (int i = tid; i < IPB * APX * 4; i += 256) {
            const int px_g = i >> 2, c = i & 3;
            int tile = 0, px = px_g;
            if (IPB == 4) { tile = px_g / APX; px = px_g - tile * APX; }
            const int gy = regY0 - 1 + px / ATX;
            const int gx = regX0 - 1 + px % ATX;
            const int bimg = (IPB == 1) ? img : ((int)blockIdx.x * 4 + tile);
            uint4 v = {0u, 0u, 0u, 0u};
            if ((unsigned)gy < (unsigned)H && (unsigned)gx < (unsigned)W)
                v = *(const uint4*)&in[((bimg * H + gy) * W + gx) * CI + cib + c * 16];
            *(uint4*)&lds[c * APLANE + px_g * 16] = v;
        }
        // --- weight staging: raw i8 [co][tap][ci-chunk] -> plane-split LDS ---
        for (int i = tid; i < 2304; i += 256) {
            const int row = i >> 2, c = i & 3;
            const int co_l = row / 9, tap = row - co_l * 9;
            uint4 v = *(const uint4*)&wt[((co_base + co_l) * 9 + tap) * CI + cib + c * 16];
            *(uint4*)&lds[WBASE + c * WPLANE + row * 16] = v;
        }
        __syncthreads();

#pragma unroll
        for (int tap = 0; tap < 9; ++tap) {
            const int toff = ((tap / 3) * ATX + (tap % 3)) * 16;
            v4i bf[4], af[4];
#pragma unroll
            for (int cs = 0; cs < 4; ++cs)
                bf[cs] = *(const v4i*)&lds[wbase[cs] + tap * 16];
#pragma unroll
            for (int ps = 0; ps < 4; ++ps)
                af[ps] = *(const v4i*)&lds[abase[ps] + toff];
#pragma unroll
            for (int ps = 0; ps < 4; ++ps)
#pragma unroll
                for (int cs = 0; cs < 4; ++cs)
                    acc[ps][cs] = __builtin_amdgcn_mfma_i32_16x16x64_i8(
                        af[ps], bf[cs], acc[ps][cs], 0, 0, 0);
        }
    }

    // --- epilogue: fp64 affine+quant+relu, optional intra-lane 2x2 pool ---
    const int bimg = (IPB == 1) ? img : ((int)blockIdx.x * 4 + w);
#pragma unroll
    for (int cs = 0; cs < 4; ++cs) {
        const int co = co_base + cs * 16 + n;
        const double gg = (double)gvec[co];
        const double bb = (double)bvec[co];
#pragma unroll
        for (int ps = 0; ps < 4; ++ps) {
            const int Yb = regY0 + wy8 + (ps >> 1) * 4 + (q >> 1) * 2;
            const int Xb = regX0 + wx8 + (ps & 1) * 4 + (q & 1) * 2;
            int r4[4];
#pragma unroll
            for (int r = 0; r < 4; ++r) {
                double conv = (double)acc[ps][cs][r] / 49.0;
                double y = conv * gg + bb;
                double t = fmin(fmax(y, -1.0), 1.0) * 7.0;
                int qi = (int)rint(t);
                r4[r] = qi > 0 ? qi : 0;
            }
            if (POOL) {
                int m = max(max(r4[0], r4[1]), max(r4[2], r4[3]));
                out[((bimg * (H / 2) + (Yb >> 1)) * (W / 2) + (Xb >> 1)) * CO + co] = (unsigned char)m;
            } else {
#pragma unroll
                for (int r = 0; r < 4; ++r) {
                    const int Y = Yb + (r >> 1), X = Xb + (r & 1);
                    out[((bimg * H + Y) * W + X) * CO + co] = (unsigned char)r4[r];
                }
            }
        }
    }
}

// ---------------------------------------------------------------------------
// FC1: h[512][4096] u8 x wt[512][4096] i8 -> u8 [512][512], i8 MFMA,
// 32x32 output tile, 4 waves split K=4096 into 1024 each, LDS reduce.
// ---------------------------------------------------------------------------
__global__ __launch_bounds__(256, 2) void fc1_i8_k(
    const unsigned char* __restrict__ h, const signed char* __restrict__ wt,
    const float* __restrict__ gvec, const float* __restrict__ bvec,
    unsigned char* __restrict__ out)
{
    __shared__ int red[4096];
    const int tid = threadIdx.x;
    const int l = tid & 63, w = tid >> 6;
    const int n = l & 15, q = l >> 4;
    const int m0 = blockIdx.x * 32, n0 = blockIdx.y * 32;

    v4i acc[2][2];
#pragma unroll
    for (int a = 0; a < 2; ++a)
#pragma unroll
        for (int b = 0; b < 2; ++b) acc[a][b] = (v4i)0;

    const int kb = w * 1024;
    for (int ks = 0; ks < 16; ++ks) {
        const int k = kb + ks * 64 + q * 16;
        v4i af[2], bf[2];
#pragma unroll
        for (int ms = 0; ms < 2; ++ms)
            af[ms] = *(const v4i*)&h[(m0 + ms * 16 + n) * 4096 + k];
#pragma unroll
        for (int ns = 0; ns < 2; ++ns)
            bf[ns] = *(const v4i*)&wt[(n0 + ns * 16 + n) * 4096 + k];
#pragma unroll
        for (int ms = 0; ms < 2; ++ms)
#pragma unroll
            for (int ns = 0; ns < 2; ++ns)
                acc[ms][ns] = __builtin_amdgcn_mfma_i32_16x16x64_i8(
                    af[ms], bf[ns], acc[ms][ns], 0, 0, 0);
    }

#pragma unroll
    for (int ms = 0; ms < 2; ++ms)
#pragma unroll
        for (int ns = 0; ns < 2; ++ns)
#pragma unroll
            for (int r = 0; r < 4; ++r)
                red[w * 1024 + (ms * 16 + q * 4 + r) * 32 + ns * 16 + n] = acc[ms][ns][r];
    __syncthreads();

#pragma unroll
    for (int j = 0; j < 4; ++j) {
        const int e = tid * 4 + j;
        int s = red[e] + red[1024 + e] + red[2048 + e] + red[3072 + e];
        const int ml = e >> 5, nl = e & 31;
        const int co = n0 + nl;
        double y = ((double)s / 49.0) * (double)gvec[co] + (double)bvec[co];
        double t = fmin(fmax(y, -1.0), 1.0) * 7.0;
        int qi = (int)rint(t);
        qi = qi > 0 ? qi : 0;
        out[(m0 + ml) * 512 + co] = (unsigned char)qi;
    }
}

// FC2: tiny
__global__ __launch_bounds__(256) void fc2_k(
    const unsigned char* __restrict__ h, const signed char* __restrict__ wq,
    const float* __restrict__ gvec, const float* __restrict__ bvec,
    float* __restrict__ out)
{
    const int gid = blockIdx.x * 256 + threadIdx.x;
    const int b = gid >> 4;
    const int n = gid & 15;
    if (b >= 512 || n >= 10) return;
    int s = 0;
    for (int k = 0; k < 512; ++k)
        s += (int)h[b * 512 + k] * (int)wq[n * 512 + k];
    double y = ((double)s / 49.0) * (double)gvec[n] + (double)bvec[n];
    double t = fmin(fmax(y, -1.0), 1.0) * 7.0;
    double r = rint(t);
    out[b * 10 + n] = (float)(r / 7.0);
}

// ---------------------------------------------------------------------------
extern "C" void kernel_launch(void* const* d_in, const int* in_sizes, int n_in,
                              void* d_out, int out_size, void* d_ws, size_t ws_size,
                              hipStream_t stream) {
    const float* x   = (const float*)d_in[0];
    const float* w1  = (const float*)d_in[1];
    const float* g1  = (const float*)d_in[2];
    const float* b1  = (const float*)d_in[3];
    const float* w2  = (const float*)d_in[4];
    const float* g2  = (const float*)d_in[5];
    const float* b2  = (const float*)d_in[6];
    const float* w3  = (const float*)d_in[7];
    const float* g3  = (const float*)d_in[8];
    const float* b3  = (const float*)d_in[9];
    const float* w4  = (const float*)d_in[10];
    const float* g4  = (const float*)d_in[11];
    const float* b4  = (const float*)d_in[12];
    const float* w5  = (const float*)d_in[13];
    const float* g5  = (const float*)d_in[14];
    const float* b5  = (const float*)d_in[15];
    const float* w6  = (const float*)d_in[16];
    const float* g6  = (const float*)d_in[17];
    const float* b6  = (const float*)d_in[18];
    const float* wf1 = (const float*)d_in[19];
    const float* gf1 = (const float*)d_in[20];
    const float* bf1 = (const float*)d_in[21];
    const float* wf2 = (const float*)d_in[22];
    const float* gf2 = (const float*)d_in[23];
    const float* bf2 = (const float*)d_in[24];

    char* ws = (char*)d_ws;
    signed char*   qw1  = (signed char*)(ws + O_QW1);
    signed char*   qwf2 = (signed char*)(ws + O_QWF2);
    signed char*   qwt2 = (signed char*)(ws + O_QWT2);
    signed char*   qwt3 = (signed char*)(ws + O_QWT3);
    signed char*   qwt4 = (signed char*)(ws + O_QWT4);
    signed char*   qwt5 = (signed char*)(ws + O_QWT5);
    signed char*   qwt6 = (signed char*)(ws + O_QWT6);
    signed char*   qwf1 = (signed char*)(ws + O_QWF1);
    unsigned char* bufA = (unsigned char*)(ws + O_BUFA);
    unsigned char* bufB = (unsigned char*)(ws + O_BUFB);

    // weight prep
    hipLaunchKernelGGL(quantw_k, dim3(7),  dim3(256), 0, stream, w1,  qw1,  1728);
    hipLaunchKernelGGL(quantw_k, dim3(20), dim3(256), 0, stream, wf2, qwf2, 5120);
    hipLaunchKernelGGL(quantw_t8_k, dim3(144),  dim3(256), 0, stream, w2, qwt2, 64,  36864);
    hipLaunchKernelGGL(quantw_t8_k, dim3(288),  dim3(256), 0, stream, w3, qwt3, 64,  73728);
    hipLaunchKernelGGL(quantw_t8_k, dim3(576),  dim3(256), 0, stream, w4, qwt4, 128, 147456);
    hipLaunchKernelGGL(quantw_t8_k, dim3(1152), dim3(256), 0, stream, w5, qwt5, 128, 294912);
    hipLaunchKernelGGL(quantw_t8_k, dim3(2304), dim3(256), 0, stream, w6, qwt6, 256, 589824);
    hipLaunchKernelGGL(quantw_fc1_k, dim3(8192), dim3(256), 0, stream, wf1, qwf1);

    // conv stack
    hipLaunchKernelGGL(conv1_k, dim3(2048, 4), dim3(256), 0, stream, x, qw1, g1, b1, bufA);
    hipLaunchKernelGGL((conv_i8_k<64,  64,  32, 32, true,  1>), dim3(2048, 1), dim3(256), 0, stream, bufA, qwt2, g2, b2, bufB);
    hipLaunchKernelGGL((conv_i8_k<64,  128, 16, 16, false, 1>), dim3(512,  2), dim3(256), 0, stream, bufB, qwt3, g3, b3, bufA);
    hipLaunchKernelGGL((conv_i8_k<128, 128, 16, 16, true,  1>), dim3(512,  2), dim3(256), 0, stream, bufA, qwt4, g4, b4, bufB);
    hipLaunchKernelGGL((conv_i8_k<128, 256, 8,  8,  false, 4>), dim3(128,  4), dim3(256), 0, stream, bufB, qwt5, g5, b5, bufA);
    hipLaunchKernelGGL((conv_i8_k<256, 256, 8,  8,  true,  4>), dim3(128,  4), dim3(256), 0, stream, bufA, qwt6, g6, b6, bufB);

    // FC head
    hipLaunchKernelGGL(fc1_i8_k, dim3(16, 16), dim3(256), 0, stream, bufB, qwf1, gf1, bf1, bufA);
    hipLaunchKernelGGL(fc2_k, dim3(32), dim3(256), 0, stream, bufA, qwf2, gf2, bf2, (float*)d_out);
}